// Round 1
// baseline (330.679 us; speedup 1.0000x reference)
//
#include <hip/hip_runtime.h>

#define N_ROWS   1048576
#define T_COLS   32
#define NBLK     1024
#define BLOCK    512
#define ROWS_PER_WAVE 256
#define CH       16                 // 16-row chunks per wave (256 rows / wave)
#define NWS      2080               // 1024 Gt + 1024 Gp + 32 colsums

typedef _Float16 half8    __attribute__((ext_vector_type(8)));
typedef _Float16 half4    __attribute__((ext_vector_type(4)));
typedef float    floatx16 __attribute__((ext_vector_type(16)));
typedef float    f32x4    __attribute__((ext_vector_type(4)));

// LDS staging: per wave, 2 buffers of [16 rows][36 f16] (72-B row stride).
// Reads (8x ds_read_u16 per MFMA): dword idx = 18*row + col/2 -> lanes 0-31
// cover banks 0-15 once, lanes 32-63 (row+8 -> +144 dwords = +16 banks) cover
// banks 16-31 once: conflict-free. Writes are half4 (b64), ~2-way worst case.
#define LDS_ROW_H   36
#define LDS_BUF_H   (16 * LDS_ROW_H)     // 576 f16 = 1152 B
#define LDS_WAVE_H  (2 * LDS_BUF_H)      // 1152 f16 = 2304 B
#define LDS_BYTES   (8 * LDS_WAVE_H * 2) // 18432 B (s_red overlays this: 8320 B needed)

// Gram via mfma_f32_32x32x16_f16 with the SAME fragment as A and B (A/B lane
// maps identical: dim=lane&31, k = (lane>>5)*8 + elem; any within-lane k-perm
// cancels A vs B; C/D transposition harmless since G is symmetric).
__global__ __launch_bounds__(BLOCK, 8) void ts_gram(const float* __restrict__ y_pred,
                                                    const float* __restrict__ y_true,
                                                    float* __restrict__ ws) {
    __shared__ alignas(16) char smem[LDS_BYTES];

    const int tid  = threadIdx.x;
    const int wv   = tid >> 6;
    const int mtx  = wv >> 2;          // 0 = y_true (waves 0-3), 1 = y_pred (waves 4-7)
    const int sub  = wv & 3;
    const int lane = tid & 63;
    const int hi   = lane >> 5;        // k-half within chunk (MFMA frag)
    const int col  = lane & 31;        // MFMA frag column
    const int lr   = lane >> 3;        // load: row within 8-row group (0..7)
    const int lg   = lane & 7;         // load: col group (4 cols each)

    const float* src = (mtx == 0) ? y_true : y_pred;
    const size_t row0 = (size_t)blockIdx.x * (4 * ROWS_PER_WAVE) + (size_t)sub * ROWS_PER_WAVE;
    const f32x4* lp = (const f32x4*)(src + row0 * T_COLS) + lg;   // + row*8 per row

    _Float16* lh = (_Float16*)smem + wv * LDS_WAVE_H;   // wave-private: no barriers in loop

    floatx16 acc = {};
    float cs[4] = {0.f, 0.f, 0.f, 0.f};
    f32x4 pf[2][2];                    // [chunk parity][q] prefetch regs (all static-indexed)

    // 8 rows x 32 cols per dwordx4 instruction: dense 1 KB, perfectly coalesced.
#define LOADC(c, dst) do {                                                  \
        (dst)[0] = lp[(size_t)(((c) * 16 + 0 + lr) * 8)];                   \
        (dst)[1] = lp[(size_t)(((c) * 16 + 8 + lr) * 8)];                   \
    } while (0)

#define STAGEC(c, s) do {                                                   \
        _Float16* wp_ = lh + (((c) & 1) * LDS_BUF_H) + lr * LDS_ROW_H + lg * 4; \
        _Pragma("unroll")                                                   \
        for (int q_ = 0; q_ < 2; ++q_) {                                    \
            f32x4 v_ = (s)[q_];                                             \
            half4 h_;                                                       \
            h_[0] = (_Float16)v_[0]; h_[1] = (_Float16)v_[1];               \
            h_[2] = (_Float16)v_[2]; h_[3] = (_Float16)v_[3];               \
            *(half4*)(wp_ + q_ * 8 * LDS_ROW_H) = h_;                       \
            if (mtx == 0) { cs[0] += v_[0]; cs[1] += v_[1];                 \
                            cs[2] += v_[2]; cs[3] += v_[3]; }               \
        }                                                                   \
    } while (0)

#define COMPUTEC(c) do {                                                    \
        const _Float16* rp_ = lh + (((c) & 1) * LDS_BUF_H) + hi * 8 * LDS_ROW_H + col; \
        half8 h_;                                                           \
        _Pragma("unroll")                                                   \
        for (int j_ = 0; j_ < 8; ++j_) h_[j_] = rp_[j_ * LDS_ROW_H];        \
        acc = __builtin_amdgcn_mfma_f32_32x32x16_f16(h_, h_, acc, 0, 0, 0); \
    } while (0)

    // Software pipeline: loads(c+2) issue BEFORE the vmcnt wait inside
    // stage(c+1); compute(c) reads the buffer written one iteration ago.
    LOADC(0, pf[0]);
    LOADC(1, pf[1]);
    STAGEC(0, pf[0]);
    #pragma unroll
    for (int c = 0; c < CH; ++c) {
        if (c + 2 < CH) LOADC(c + 2, pf[c & 1]);           // pf[c&1] (chunk c) already staged
        if (c + 1 < CH) STAGEC(c + 1, pf[(c + 1) & 1]);
        COMPUTEC(c);
    }

    // ---- block reduction (s_red overlays staging LDS) ----
    __syncthreads();                       // all waves done with staging buffers
    float* s_red = (float*)smem;
    for (int i = tid; i < NWS; i += BLOCK) s_red[i] = 0.0f;
    __syncthreads();
    // C/D layout (m74/m101, dtype-independent): col=lane&31,
    // row=(r&3)+8*(r>>2)+4*(lane>>5). 4-way collisions (sub 0..3).
    #pragma unroll
    for (int r = 0; r < 16; ++r) {
        int row = (r & 3) + 8 * (r >> 2) + 4 * hi;
        atomicAdd(&s_red[mtx * 1024 + row * 32 + col], acc[r]);
    }
    if (mtx == 0) {
        // reduce colsums over lr (lane bits 3..5); lane's comp k is col lg*4+k
        #pragma unroll
        for (int k = 0; k < 4; ++k) {
            cs[k] += __shfl_xor(cs[k], 8);
            cs[k] += __shfl_xor(cs[k], 16);
            cs[k] += __shfl_xor(cs[k], 32);
        }
        if (lr == 0) {
            #pragma unroll
            for (int k = 0; k < 4; ++k) atomicAdd(&s_red[2048 + lg * 4 + k], cs[k]);
        }
    }
    __syncthreads();
    for (int i = tid; i < NWS; i += BLOCK) atomicAdd(&ws[i], s_red[i]);
}

__global__ __launch_bounds__(1024) void ts_final(const float* __restrict__ w,
                                                 float* __restrict__ out) {
    __shared__ float s_S[32], s_nx[32], s_pn[32];
    __shared__ float s_red[16];
    const int tid = threadIdx.x;
    const float invN = 1.0f / (float)N_ROWS;

    if (tid < 32) {
        float S = w[2048 + tid];
        s_S[tid] = S;
        float d = w[tid * 32 + tid] - S * S * invN;   // centered diag
        s_nx[tid] = sqrtf(d);
        s_pn[tid] = sqrtf(w[1024 + tid * 33]);
    }
    __syncthreads();

    const int j = tid >> 5, k = tid & 31;
    float contrib = 0.0f;
    if (j >= 1 && k > j) {
        float gc  = w[j * 32 + k] - s_S[j] * s_S[k] * invN;
        float pcc = gc / (s_nx[j] * s_nx[k]);
        float cs  = w[1024 + j * 32 + k] / fmaxf(s_pn[j] * s_pn[k], 1e-8f);
        if (pcc >= 0.0f) contrib = 1.0f - cs;
    }
    #pragma unroll
    for (int off = 32; off > 0; off >>= 1) contrib += __shfl_down(contrib, off);
    if ((tid & 63) == 0) s_red[tid >> 6] = contrib;
    __syncthreads();
    if (tid == 0) {
        float tot = 0.0f;
        #pragma unroll
        for (int i = 0; i < 16; ++i) tot += s_red[i];
        out[0] = tot * (1.0f / 465.0f);   // c = (T-1)(T-2)/2
    }
}

extern "C" void kernel_launch(void* const* d_in, const int* in_sizes, int n_in,
                              void* d_out, int out_size, void* d_ws, size_t ws_size,
                              hipStream_t stream) {
    const float* y_pred = (const float*)d_in[0];
    const float* y_true = (const float*)d_in[1];
    float* out = (float*)d_out;
    float* ws  = (float*)d_ws;

    hipMemsetAsync(ws, 0, NWS * sizeof(float), stream);
    ts_gram<<<NBLK, BLOCK, 0, stream>>>(y_pred, y_true, ws);
    ts_final<<<1, 1024, 0, stream>>>(ws, out);
}

// Round 2
// 292.744 us; speedup vs baseline: 1.1296x; 1.1296x over previous
//
#include <hip/hip_runtime.h>

#define N_ROWS   1048576
#define T_COLS   32
#define NBLK     1024
#define BLOCK    512
#define ROWS_PER_WAVE 256
#define CH       16                 // 16-row chunks per wave (256 rows / wave)
#define NWS      2080               // 1024 Gt + 1024 Gp + 32 colsums

typedef _Float16 half8    __attribute__((ext_vector_type(8)));
typedef float    floatx16 __attribute__((ext_vector_type(16)));

// Per-wave LDS: double-buffered 16x32 f32 chunk (2 KB each).
// global_load_lds width=16: lane l -> LDS base + l*16 == row (l>>3), cols (l&7)*4..+3
// -> linear row-major [16][32] f32, written by 2 DMA instructions per chunk.
#define CHUNK_BYTES 2048
#define WAVE_BYTES  (2 * CHUNK_BYTES)
#define LDS_BYTES   (8 * WAVE_BYTES)     // 32 KiB; s_red (8320 B) overlays after loop

// Gram via mfma_f32_32x32x16_f16 with the SAME fragment as A and B (A/B lane
// maps identical: dim=lane&31, k=(lane>>5)*8+elem; any within-lane k-perm
// cancels A vs B; C/D transposition harmless since G is symmetric).
__global__ __launch_bounds__(BLOCK, 8) void ts_gram(const float* __restrict__ y_pred,
                                                    const float* __restrict__ y_true,
                                                    float* __restrict__ ws) {
    __shared__ alignas(16) char smem[LDS_BYTES];

    const int tid  = threadIdx.x;
    const int wv   = tid >> 6;
    const int mtx  = wv >> 2;          // 0 = y_true (waves 0-3), 1 = y_pred (waves 4-7)
    const int sub  = wv & 3;
    const int lane = tid & 63;
    const int hi   = lane >> 5;        // k-half within chunk (MFMA frag)
    const int col  = lane & 31;        // MFMA frag column

    const float* src = (mtx == 0) ? y_true : y_pred;
    const size_t row0 = (size_t)blockIdx.x * (4 * ROWS_PER_WAVE) + (size_t)sub * ROWS_PER_WAVE;
    // per-lane DMA source: row = row0 + (lane>>3) [+ chunk*16 + q*8], cols (lane&7)*4..+3
    const float* gp = src + (row0 + (size_t)(lane >> 3)) * T_COLS + (lane & 7) * 4;

    char* lbase = smem + wv * WAVE_BYTES;   // wave-private: no barriers in loop

#define ISSUE(c) do {                                                         \
        char* lb_ = lbase + (((c) & 1) * CHUNK_BYTES);                        \
        const float* g_ = gp + (size_t)((c) * 16) * T_COLS;                   \
        __builtin_amdgcn_global_load_lds(                                     \
            (const __attribute__((address_space(1))) void*)g_,                \
            (__attribute__((address_space(3))) void*)lb_, 16, 0, 0);          \
        __builtin_amdgcn_global_load_lds(                                     \
            (const __attribute__((address_space(1))) void*)(g_ + 8 * T_COLS), \
            (__attribute__((address_space(3))) void*)(lb_ + 1024), 16, 0, 0); \
    } while (0)

    floatx16 acc = {};
    float cs = 0.0f;

    ISSUE(0);
    ISSUE(1);

    #pragma unroll
    for (int c = 0; c < CH; ++c) {
        // chunk c must be resident; chunk c+1's 2 loads may stay in flight
        if (c + 1 < CH) { asm volatile("s_waitcnt vmcnt(2)" ::: "memory"); }
        else            { asm volatile("s_waitcnt vmcnt(0)" ::: "memory"); }
        __builtin_amdgcn_sched_barrier(0);

        // frag read: lds[hi*8+j][col] -> bank=col, 2 lanes/bank = conflict-free
        const float* rp = (const float*)(lbase + (c & 1) * CHUNK_BYTES)
                          + (size_t)hi * 8 * T_COLS + col;
        float v[8];
        #pragma unroll
        for (int j = 0; j < 8; ++j) v[j] = rp[j * T_COLS];

        // values in VGPRs before the DMA below overwrites this buffer
        asm volatile("s_waitcnt lgkmcnt(0)" ::: "memory");
        __builtin_amdgcn_sched_barrier(0);
        if (c + 2 < CH) ISSUE(c + 2);

        half8 h;
        #pragma unroll
        for (int j = 0; j < 8; ++j) h[j] = (_Float16)v[j];
        if (mtx == 0) {                 // wave-uniform branch; colsum in fp32
            #pragma unroll
            for (int j = 0; j < 8; ++j) cs += v[j];
        }
        acc = __builtin_amdgcn_mfma_f32_32x32x16_f16(h, h, acc, 0, 0, 0);
    }
#undef ISSUE

    // ---- block reduction (s_red overlays staging LDS; all DMA drained) ----
    __syncthreads();
    float* s_red = (float*)smem;
    for (int i = tid; i < NWS; i += BLOCK) s_red[i] = 0.0f;
    __syncthreads();
    // C/D layout (m74/m101, dtype-independent): col=lane&31,
    // row=(r&3)+8*(r>>2)+4*(lane>>5). 4-way collisions (sub 0..3).
    #pragma unroll
    for (int r = 0; r < 16; ++r) {
        int row = (r & 3) + 8 * (r >> 2) + 4 * hi;
        atomicAdd(&s_red[mtx * 1024 + row * 32 + col], acc[r]);
    }
    if (mtx == 0) {
        // lane holds column-col partial sum over its hi-half rows
        cs += __shfl_xor(cs, 32);
        if (lane < 32) atomicAdd(&s_red[2048 + col], cs);   // 4-way collisions
    }
    __syncthreads();
    for (int i = tid; i < NWS; i += BLOCK) atomicAdd(&ws[i], s_red[i]);
}

__global__ __launch_bounds__(1024) void ts_final(const float* __restrict__ w,
                                                 float* __restrict__ out) {
    __shared__ float s_S[32], s_nx[32], s_pn[32];
    __shared__ float s_red[16];
    const int tid = threadIdx.x;
    const float invN = 1.0f / (float)N_ROWS;

    if (tid < 32) {
        float S = w[2048 + tid];
        s_S[tid] = S;
        float d = w[tid * 32 + tid] - S * S * invN;   // centered diag
        s_nx[tid] = sqrtf(d);
        s_pn[tid] = sqrtf(w[1024 + tid * 33]);
    }
    __syncthreads();

    const int j = tid >> 5, k = tid & 31;
    float contrib = 0.0f;
    if (j >= 1 && k > j) {
        float gc  = w[j * 32 + k] - s_S[j] * s_S[k] * invN;
        float pcc = gc / (s_nx[j] * s_nx[k]);
        float cs  = w[1024 + j * 32 + k] / fmaxf(s_pn[j] * s_pn[k], 1e-8f);
        if (pcc >= 0.0f) contrib = 1.0f - cs;
    }
    #pragma unroll
    for (int off = 32; off > 0; off >>= 1) contrib += __shfl_down(contrib, off);
    if ((tid & 63) == 0) s_red[tid >> 6] = contrib;
    __syncthreads();
    if (tid == 0) {
        float tot = 0.0f;
        #pragma unroll
        for (int i = 0; i < 16; ++i) tot += s_red[i];
        out[0] = tot * (1.0f / 465.0f);   // c = (T-1)(T-2)/2
    }
}

extern "C" void kernel_launch(void* const* d_in, const int* in_sizes, int n_in,
                              void* d_out, int out_size, void* d_ws, size_t ws_size,
                              hipStream_t stream) {
    const float* y_pred = (const float*)d_in[0];
    const float* y_true = (const float*)d_in[1];
    float* out = (float*)d_out;
    float* ws  = (float*)d_ws;

    hipMemsetAsync(ws, 0, NWS * sizeof(float), stream);
    ts_gram<<<NBLK, BLOCK, 0, stream>>>(y_pred, y_true, ws);
    ts_final<<<1, 1024, 0, stream>>>(ws, out);
}